// Round 11
// baseline (278.488 us; speedup 1.0000x reference)
//
#include <hip/hip_runtime.h>
#include <stdint.h>

#define H_ 4
#define N_ 512
#define D_ 64
#define E_ (N_ * N_)        // 262144 edges per head
#define HE_ (H_ * E_)       // 1048576
#define EPS_ 1e-10f

// Partitionable threefry (verified rounds 1-3): counter (hi=0, lo=j), out = x0^x1.
__device__ __forceinline__ void tf2x32(unsigned x0, unsigned x1,
                                       unsigned& o0, unsigned& o1) {
  const unsigned ks0 = 0u;          // key hi of seed 42
  const unsigned ks1 = 42u;         // key lo
  const unsigned ks2 = 0x1BD11BDAu ^ ks0 ^ ks1;
  x0 += ks0; x1 += ks1;
#define TFR(r) { x0 += x1; x1 = (x1 << (r)) | (x1 >> (32 - (r))); x1 ^= x0; }
  TFR(13) TFR(15) TFR(26) TFR(6)
  x0 += ks1; x1 += ks2 + 1u;
  TFR(17) TFR(29) TFR(16) TFR(24)
  x0 += ks2; x1 += ks0 + 2u;
  TFR(13) TFR(15) TFR(26) TFR(6)
  x0 += ks0; x1 += ks1 + 3u;
  TFR(17) TFR(29) TFR(16) TFR(24)
  x0 += ks1; x1 += ks2 + 4u;
  TFR(13) TFR(15) TFR(26) TFR(6)
  x0 += ks2; x1 += ks0 + 5u;
#undef TFR
  o0 = x0; o1 = x1;
}

__device__ __forceinline__ unsigned rng_bits(unsigned j) {
  unsigned a, b;
  tf2x32(0u, j, a, b);
  return a ^ b;
}

__device__ __forceinline__ float u01(unsigned bits) {
  return __uint_as_float((bits >> 9) | 0x3f800000u) - 1.0f;
}

// ---------------- single fused kernel.
// Round-10 lesson: the tail re-scan must be MULTI-BLOCK (1-block/head was
// ~150 us of serial ~900-cyc loads; compiler refused the 8-deep batch,
// VGPR_Count=36 proved it). New tail: the last 64 arrivals per head split
// the scan 16 KB each; block #511 publishes the threshold via a one-way
// ready-flag (one cacheline, 63 bounded pollers -- NOT round-8's all-to-all
// barrier). Round-8 lesson: no grid barrier. Round-3: static indexing only.
__global__ __launch_bounds__(256, 4) void edge_topk(
    const float* __restrict__ feats, const float* __restrict__ W_out,
    const float* __restrict__ b_out, const float* __restrict__ W_cat,
    const float* __restrict__ b_cat, float* __restrict__ out,
    unsigned long long* __restrict__ blockmax,
    unsigned long long* __restrict__ cand,
    unsigned long long* __restrict__ thrG, unsigned* __restrict__ ctrl) {
  __shared__ __align__(16) float Ash[32][68];   // stride 68: rows 16B-aligned,
                                                // stride%32==4: full bank spread
  __shared__ __align__(16) float Bsh[16][64];
  __shared__ __align__(16) float FX[16][64];    // feats staging scratch (4 KB)
  __shared__ float4 bsh4[16];
  __shared__ float4 wc4[32];
  __shared__ float bc2[2];
  __shared__ unsigned long long wmax[4];
  __shared__ unsigned long long thrS;
  __shared__ unsigned tkS;

  unsigned* done  = ctrl;        // [0..3]  arrival counter (stage 1)
  unsigned* ready = ctrl + 4;    // [4..7]  thr-published flag
  unsigned* done2 = ctrl + 8;    // [8..11] scan arrival counter (stage 2)
  unsigned* cnt   = ctrl + 12;   // [12..15] candidate count

  const int t = threadIdx.x;
  const int h = blockIdx.z;
  const int snd_base = blockIdx.x * 32;
  const int rec_base = blockIdx.y * 16;
  const int chunk = blockIdx.y * 16 + blockIdx.x;   // 0..511 within head

  if (t < 16) bsh4[t] = ((const float4*)b_out)[t];
  else if (t < 48) wc4[t - 16] = ((const float4*)W_cat)[t - 16];
  else if (t == 48) { bc2[0] = b_cat[0]; bc2[1] = b_cat[1]; }

  // ======== phase A: block-local A/B projection (chain == precompute_ab) ====
  const int d = t & 63;
  const int g4 = (t >> 6) * 4;                  // 4 rows per thread-group
  const float4* F4 = (const float4*)feats;

#pragma unroll
  for (int half = 0; half < 2; ++half) {        // A rows: 2 halves of 16
    *(float4*)&FX[t >> 4][(t & 15) << 2] =
        F4[(h * N_ + snd_base + half * 16 + (t >> 4)) * 16 + (t & 15)];
    __syncthreads();
    float a0 = 0.f, a1 = 0.f, a2 = 0.f, a3 = 0.f;
#pragma unroll 8
    for (int k = 0; k < D_; ++k) {
      const float w = W_out[k * D_ + d];        // coalesced, L2-hot
      a0 = fmaf(FX[g4 + 0][k], w, a0);
      a1 = fmaf(FX[g4 + 1][k], w, a1);
      a2 = fmaf(FX[g4 + 2][k], w, a2);
      a3 = fmaf(FX[g4 + 3][k], w, a3);
    }
    Ash[half * 16 + g4 + 0][d] = a0;
    Ash[half * 16 + g4 + 1][d] = a1;
    Ash[half * 16 + g4 + 2][d] = a2;
    Ash[half * 16 + g4 + 3][d] = a3;
    __syncthreads();
  }
  {                                             // B rows: 16 rec rows
    *(float4*)&FX[t >> 4][(t & 15) << 2] =
        F4[(h * N_ + rec_base + (t >> 4)) * 16 + (t & 15)];
    __syncthreads();
    float b0 = 0.f, b1 = 0.f, b2 = 0.f, b3 = 0.f;
#pragma unroll 8
    for (int k = 0; k < D_; ++k) {
      const float w = W_out[(k + D_) * D_ + d]; // receiver rows [64,128)
      b0 = fmaf(FX[g4 + 0][k], w, b0);
      b1 = fmaf(FX[g4 + 1][k], w, b1);
      b2 = fmaf(FX[g4 + 2][k], w, b2);
      b3 = fmaf(FX[g4 + 3][k], w, b3);
    }
    Bsh[g4 + 0][d] = b0;
    Bsh[g4 + 1][d] = b1;
    Bsh[g4 + 2][d] = b2;
    Bsh[g4 + 3][d] = b3;
    __syncthreads();
  }

  // ======== phase B: edge math (verbatim verified FP chains) ========
  const int s = t & 31;            // sender lane
  const int rg = (t >> 5) * 2;     // receiver group (2 rec/thread)

  float l0[2], l1[2];
#pragma unroll
  for (int r = 0; r < 2; ++r) { l0[r] = 0.f; l1[r] = 0.f; }

#pragma unroll
  for (int d4 = 0; d4 < 16; ++d4) {
    const float4 a0 = *(const float4*)&Ash[s][d4 << 2];
    const float4 bd = bsh4[d4];
    const float4 wA = wc4[2 * d4];
    const float4 wB = wc4[2 * d4 + 1];
#pragma unroll
    for (int r = 0; r < 2; ++r) {
      const float4 bv = *(const float4*)&Bsh[rg + r][d4 << 2];
      float t0;
      t0 = fmaxf((a0.x + bv.x) + bd.x, 0.f);
      l0[r] = fmaf(t0, wA.x, l0[r]); l1[r] = fmaf(t0, wA.y, l1[r]);
      t0 = fmaxf((a0.y + bv.y) + bd.y, 0.f);
      l0[r] = fmaf(t0, wA.z, l0[r]); l1[r] = fmaf(t0, wA.w, l1[r]);
      t0 = fmaxf((a0.z + bv.z) + bd.z, 0.f);
      l0[r] = fmaf(t0, wB.x, l0[r]); l1[r] = fmaf(t0, wB.y, l1[r]);
      t0 = fmaxf((a0.w + bv.w) + bd.w, 0.f);
      l0[r] = fmaf(t0, wB.z, l0[r]); l1[r] = fmaf(t0, wB.w, l1[r]);
    }
  }

  unsigned long long mk = 0ull;
#pragma unroll
  for (int r = 0; r < 2; ++r) {
    float L0 = l0[r] + bc2[0];
    float L1 = l1[r] + bc2[1];
    const unsigned snd = (unsigned)(snd_base + s);
    const unsigned rec = (unsigned)(rec_base + rg + r);
    const unsigned e = rec * (unsigned)N_ + snd;
    const unsigned base = ((unsigned)h << 18) + e;
    const unsigned j0 = base * 2u;

    float uu0 = u01(rng_bits(j0));
    float uu1 = u01(rng_bits(j0 + 1u));
    float g0 = -logf(-logf(uu0 + EPS_) + EPS_);
    float g1 = -logf(-logf(uu1 + EPS_) + EPS_);

    // argmax(softmax((l+g)/0.5)) == (L1+g1 > L0+g0): /0.5 exact, softmax monotone
    float cm = ((L1 + g1) > (L0 + g0)) ? 1.0f : 0.0f;

    float lm = fmaxf(L0, L1);
    float p0 = expf(L0 - lm), p1 = expf(L1 - lm);
    float pr = p1 / (p0 + p1);

    out[base] = cm;
    out[HE_ + base] = pr;

    unsigned long long key =
        ((unsigned long long)__float_as_uint(pr) << 32) | (unsigned)(~e);
    mk = key > mk ? key : mk;
  }

  // zero this block's flat 512-edge sparse chunk (winners scattered later)
  {
    float4* sp = (float4*)(out + 2 * HE_ + ((unsigned)h << 18) +
                           (unsigned)chunk * 512u);
    if (t < 128) sp[t] = make_float4(0.f, 0.f, 0.f, 0.f);
  }

#pragma unroll
  for (int off = 32; off; off >>= 1) {
    unsigned long long o = __shfl_xor(mk, off, 64);
    mk = o > mk ? o : mk;
  }
  if ((t & 63) == 0) wmax[t >> 6] = mk;
  __syncthreads();
  if (t == 0) {
    unsigned long long m = wmax[0];
#pragma unroll
    for (int i = 1; i < 4; ++i) m = wmax[i] > m ? wmax[i] : m;
    blockmax[h * 512 + chunk] = m;               // 512 chunks/head
  }

  // -------- stage-1 arrival (verified release/acquire pattern) --------
  __syncthreads();
  if (t == 0) { __threadfence(); tkS = atomicAdd(&done[h], 1u); }  // release
  __syncthreads();
  const unsigned arr = tkS;
  if (arr < 448u) return;        // only the last 64 arrivals run the tail

  unsigned long long* keyS = (unsigned long long*)&Ash[0][0];   // 4 KB
  if (arr == 511u) {
    // last arrival: all blockmax/pr stores are globally visible (each writer
    // fenced before its arrival). Compute thr = 64th-largest chunk max
    // (exact; keys unique; >=64 elements have key >= thr so all top-64
    // survive), publish, release ready-flag.
    if (t == 0) __threadfence();               // acquire
    __syncthreads();
    keyS[t] = blockmax[h * 512 + t];
    keyS[t + 256] = blockmax[h * 512 + 256 + t];
    __syncthreads();
    {
      unsigned long long k0 = keyS[t], k1 = keyS[t + 256];
      int r0 = 0, r1 = 0;
      for (int j = 0; j < 512; ++j) {
        unsigned long long kj = keyS[j];
        r0 += (kj > k0);
        r1 += (kj > k1);
      }
      if (r0 == 63) thrS = k0;
      if (r1 == 63) thrS = k1;
    }
    __syncthreads();
    if (t == 0) {
      thrG[h * 16] = thrS;                     // own cacheline per head
      __threadfence();                         // release thr
      atomicAdd(&ready[h], 1u);
    }
  } else {
    // arrivals 448..510: bounded one-way poll for the ready flag (the
    // publisher is by definition already running -> no circular wait).
    if (t == 0) {
      for (long i = 0; i < 30000000L; ++i) {
        if (__hip_atomic_load(&ready[h], __ATOMIC_RELAXED,
                              __HIP_MEMORY_SCOPE_AGENT) != 0u)
          break;
        __builtin_amdgcn_s_sleep(2);
      }
      __threadfence();                         // acquire thr
      thrS = thrG[h * 16];
    }
    __syncthreads();
  }
  const unsigned long long thr = thrS;

  // -------- parallel scan: 64 blocks x 4096 edges (16 KB) each --------
  {
    const unsigned seg = arr - 448u;           // 0..63
    const float4* P4 =
        (const float4*)(out + HE_ + ((unsigned)h << 18) + seg * 4096u);
    float4 b0 = P4[t];
    float4 b1 = P4[256 + t];
    float4 b2 = P4[512 + t];
    float4 b3 = P4[768 + t];
    const float pv[16] = {b0.x, b0.y, b0.z, b0.w, b1.x, b1.y, b1.z, b1.w,
                          b2.x, b2.y, b2.z, b2.w, b3.x, b3.y, b3.z, b3.w};
#pragma unroll
    for (int k = 0; k < 16; ++k) {
      const unsigned e = seg * 4096u + (unsigned)(k >> 2) * 1024u +
                         (unsigned)t * 4u + (unsigned)(k & 3);
      unsigned long long key =
          ((unsigned long long)__float_as_uint(pv[k]) << 32) | (unsigned)(~e);
      if (key >= thr) {
        unsigned pos = atomicAdd(&cnt[h], 1u);   // ~155 expected << 512
        if (pos < 512u) cand[h * 512 + pos] = key;
      }
    }
  }

  // -------- stage-2 arrival: last of the 64 does the final select --------
  __syncthreads();
  if (t == 0) { __threadfence(); tkS = atomicAdd(&done2[h], 1u); }  // release
  __syncthreads();
  if (tkS != 63u) return;
  if (t == 0) __threadfence();                 // acquire
  __syncthreads();

  unsigned n = atomicAdd(&cnt[h], 0u);         // coherent final count
  if (n > 512u) n = 512u;
  unsigned long long m0 = (t < (int)n) ? cand[h * 512 + t] : 0ull;
  unsigned long long m1 = (t + 256 < (int)n) ? cand[h * 512 + t + 256] : 0ull;
  keyS[t] = m0;
  keyS[t + 256] = m1;
  __syncthreads();
  {
    int r0 = 0, r1 = 0;
#pragma unroll 8
    for (int j = 0; j < 512; ++j) {
      unsigned long long kj = keyS[j];
      r0 += (kj > m0);
      r1 += (kj > m1);
    }
    if (m0 != 0ull && r0 < 64) {
      unsigned e = ~(unsigned)(m0 & 0xFFFFFFFFull);
      if (e < (unsigned)E_) out[2 * HE_ + ((unsigned)h << 18) + e] = 1.0f;
    }
    if (m1 != 0ull && r1 < 64) {
      unsigned e = ~(unsigned)(m1 & 0xFFFFFFFFull);
      if (e < (unsigned)E_) out[2 * HE_ + ((unsigned)h << 18) + e] = 1.0f;
    }
  }
}

extern "C" void kernel_launch(void* const* d_in, const int* in_sizes, int n_in,
                              void* d_out, int out_size, void* d_ws, size_t ws_size,
                              hipStream_t stream) {
  const float* feats = (const float*)d_in[0];
  const float* W_out = (const float*)d_in[1];
  const float* b_out = (const float*)d_in[2];
  const float* W_cat = (const float*)d_in[3];
  const float* b_cat = (const float*)d_in[4];
  float* out = (float*)d_out;

  // workspace: blockmax(H*512 ull) | cand(H*512 ull) | thrG(H*16 ull) | ctrl(16 u32)
  unsigned long long* blockmax = (unsigned long long*)d_ws;
  unsigned long long* cand = blockmax + H_ * 512;
  unsigned long long* thrG = cand + H_ * 512;
  unsigned* ctrl = (unsigned*)(thrG + H_ * 16);

  // zero the 16 control words (done/ready/done2/cnt); stream-ordered memset
  // is graph-capture legal (verified round 8).
  hipMemsetAsync((void*)ctrl, 0, 16 * sizeof(unsigned), stream);

  edge_topk<<<dim3(N_ / 32, N_ / 16, H_), dim3(256), 0, stream>>>(
      feats, W_out, b_out, W_cat, b_cat, out, blockmax, cand, thrG, ctrl);
}